// Round 5
// baseline (1412.961 us; speedup 1.0000x reference)
//
#include <hip/hip_runtime.h>

// Forward multivariate 3rd-order jet propagation through the 9-layer tanh MLP.
// Components per neuron: 0:v 1:x 2:y 3:t 4:xx 5:xy 6:yy 7:xt 8:yt 9:xxx 10:xxy 11:xyy 12:yyy
namespace {
constexpr int HN = 20;
constexpr int NC = 13;

__device__ __forceinline__ float fast_tanh(float v) {
    float e = __expf(2.0f * v);      // saturates: +inf -> 1, 0 -> -1
    return 1.0f - 2.0f / (e + 1.0f);
}
}

__global__ __launch_bounds__(256, 1)
void ns_pinn_kernel(const float* __restrict__ gx, const float* __restrict__ gy,
                    const float* __restrict__ gt,
                    const float* __restrict__ W0, const float* __restrict__ b0,
                    const float* __restrict__ Wh, const float* __restrict__ bh,
                    const float* __restrict__ W9, const float* __restrict__ b9,
                    const float* __restrict__ lam1, const float* __restrict__ lam2,
                    float* __restrict__ out, int n)
{
    int i = blockIdx.x * blockDim.x + threadIdx.x;
    if (i >= n) return;

    const float xi = gx[i], yi = gy[i], ti = gt[i];

    float h[NC][HN];

    // ---- layer 0: s is affine in (x,y,t); higher jet comps of s are 0 ----
#pragma unroll
    for (int j = 0; j < HN; ++j) {
        const float w0 = W0[j*3+0], w1 = W0[j*3+1], w2 = W0[j*3+2];
        const float sv = fmaf(w0, xi, fmaf(w1, yi, fmaf(w2, ti, b0[j])));
        const float f  = fast_tanh(sv);
        const float g1 = 1.0f - f*f;            // f'
        const float g2 = -2.0f*f*g1;            // f''
        const float g3 = -2.0f*(g1*g1 + f*g2);  // f'''
        h[0][j] = f;
        h[1][j] = g1*w0; h[2][j] = g1*w1; h[3][j] = g1*w2;
        h[4][j] = g2*w0*w0; h[5][j] = g2*w0*w1; h[6][j] = g2*w1*w1;
        h[7][j] = g2*w0*w2; h[8][j] = g2*w1*w2;
        h[9][j]  = g3*w0*w0*w0;
        h[10][j] = g3*w0*w0*w1;
        h[11][j] = g3*w0*w1*w1;
        h[12][j] = g3*w1*w1*w1;
    }

    // ---- 8 hidden layers ----
    for (int l = 0; l < 8; ++l) {
        const float* __restrict__ W  = Wh + l*HN*HN;
        const float* __restrict__ bb = bh + l*HN;
        // Affine part is component-wise independent -> in-place via 20-reg temp
        // (avoids a full 260-reg double buffer).
#pragma unroll
        for (int c = 0; c < NC; ++c) {
            float tmp[HN];
#pragma unroll
            for (int j = 0; j < HN; ++j) {
                float acc = (c == 0) ? bb[j] : 0.0f;
#pragma unroll
                for (int k = 0; k < HN; ++k)
                    acc = fmaf(W[j*HN+k], h[c][k], acc);
                tmp[j] = acc;
            }
#pragma unroll
            for (int j = 0; j < HN; ++j) h[c][j] = tmp[j];
        }
        // tanh jet per neuron (3rd-order chain rule), in place
#pragma unroll
        for (int j = 0; j < HN; ++j) {
            const float sv=h[0][j], sx=h[1][j], sy=h[2][j], st=h[3][j],
                        sxx=h[4][j], sxy=h[5][j], syy=h[6][j], sxt=h[7][j], syt=h[8][j],
                        sxxx=h[9][j], sxxy=h[10][j], sxyy=h[11][j], syyy=h[12][j];
            const float f  = fast_tanh(sv);
            const float g1 = 1.0f - f*f;
            const float g2 = -2.0f*f*g1;
            const float g3 = -2.0f*(g1*g1 + f*g2);
            h[0][j] = f;
            h[1][j] = g1*sx; h[2][j] = g1*sy; h[3][j] = g1*st;
            h[4][j] = fmaf(g2, sx*sx, g1*sxx);
            h[5][j] = fmaf(g2, sx*sy, g1*sxy);
            h[6][j] = fmaf(g2, sy*sy, g1*syy);
            h[7][j] = fmaf(g2, sx*st, g1*sxt);
            h[8][j] = fmaf(g2, sy*st, g1*syt);
            h[9][j]  = g3*sx*sx*sx + 3.0f*g2*sx*sxx + g1*sxxx;
            h[10][j] = g3*sx*sx*sy + g2*(2.0f*sx*sxy + sy*sxx) + g1*sxxy;
            h[11][j] = g3*sx*sy*sy + g2*(2.0f*sy*sxy + sx*syy) + g1*sxyy;
            h[12][j] = g3*sy*sy*sy + 3.0f*g2*sy*syy + g1*syyy;
        }
    }

    // ---- output layer (affine, no tanh): row 0 = psi jet, row 1 = p (v,x,y only) ----
    float psiC[NC];
#pragma unroll
    for (int c = 0; c < NC; ++c) {
        float acc = (c == 0) ? b9[0] : 0.0f;
#pragma unroll
        for (int k = 0; k < HN; ++k) acc = fmaf(W9[k], h[c][k], acc);
        psiC[c] = acc;
    }
    float pv = b9[1], px = 0.0f, py = 0.0f;
#pragma unroll
    for (int k = 0; k < HN; ++k) {
        const float w = W9[HN + k];
        pv = fmaf(w, h[0][k], pv);
        px = fmaf(w, h[1][k], px);
        py = fmaf(w, h[2][k], py);
    }

    const float l1 = lam1[0], l2 = lam2[0];
    const float u    = psiC[2];          // psi_y
    const float v    = -psiC[1];         // -psi_x
    const float u_x  = psiC[5];          // psi_xy
    const float u_y  = psiC[6];          // psi_yy
    const float u_t  = psiC[8];          // psi_yt
    const float u_xx = psiC[10];         // psi_xxy
    const float u_yy = psiC[12];         // psi_yyy
    const float v_x  = -psiC[4];         // -psi_xx
    const float v_y  = -psiC[5];         // -psi_xy
    const float v_t  = -psiC[7];         // -psi_xt
    const float v_xx = -psiC[9];         // -psi_xxx
    const float v_yy = -psiC[11];        // -psi_xyy

    const float fo = u_t + l1*(u*u_x + v*u_y) + px - l2*(u_xx + u_yy);
    const float go = v_t + l1*(u*v_x + v*v_y) + py - l2*(v_xx + v_yy);

    float* o = out + (size_t)i * 5;
    o[0] = u; o[1] = v; o[2] = pv; o[3] = fo; o[4] = go;
}

extern "C" void kernel_launch(void* const* d_in, const int* in_sizes, int n_in,
                              void* d_out, int out_size, void* d_ws, size_t ws_size,
                              hipStream_t stream)
{
    const float* x    = (const float*)d_in[0];
    const float* y    = (const float*)d_in[1];
    const float* t    = (const float*)d_in[2];
    const float* W0   = (const float*)d_in[3];
    const float* b0   = (const float*)d_in[4];
    const float* Wh   = (const float*)d_in[5];
    const float* bh   = (const float*)d_in[6];
    const float* W9   = (const float*)d_in[7];
    const float* b9   = (const float*)d_in[8];
    const float* lam1 = (const float*)d_in[9];
    const float* lam2 = (const float*)d_in[10];
    const int n = in_sizes[0];
    float* outp = (float*)d_out;

    const int block = 256;
    const int grid = (n + block - 1) / block;
    hipLaunchKernelGGL(ns_pinn_kernel, dim3(grid), dim3(block), 0, stream,
                       x, y, t, W0, b0, Wh, bh, W9, b9, lam1, lam2, outp, n);
}